// Round 1
// baseline (47.600 us; speedup 1.0000x reference)
//
#include <hip/hip_runtime.h>

#define DH 512
#define NB 1024
#define BLOCK 256
#define EPS 1e-6f

__global__ __launch_bounds__(BLOCK) void siamese_partial(
    const float* __restrict__ x1, const float* __restrict__ x2,
    const float* __restrict__ y1, const float* __restrict__ y2,
    const float* __restrict__ yp1, float* __restrict__ partial, int B)
{
    const int lane = threadIdx.x & 63;
    const int wib  = threadIdx.x >> 6;                       // wave in block
    const int wid  = blockIdx.x * (BLOCK >> 6) + wib;        // global wave id
    const int nw   = gridDim.x * (BLOCK >> 6);               // total waves

    float acc = 0.0f;

    for (int row = wid; row < B; row += nw) {
        const size_t base = (size_t)row * DH;
        const float4* p1 = reinterpret_cast<const float4*>(x1 + base) + lane * 2;
        const float4* p2 = reinterpret_cast<const float4*>(x2 + base) + lane * 2;
        float4 a0 = p1[0], a1 = p1[1];
        float4 b0 = p2[0], b1 = p2[1];

        float ssq = 0.0f;
        bool eq = true;
        float d;
        d = a0.x - b0.x; ssq = fmaf(d, d, ssq); eq = eq && (a0.x == b0.x);
        d = a0.y - b0.y; ssq = fmaf(d, d, ssq); eq = eq && (a0.y == b0.y);
        d = a0.z - b0.z; ssq = fmaf(d, d, ssq); eq = eq && (a0.z == b0.z);
        d = a0.w - b0.w; ssq = fmaf(d, d, ssq); eq = eq && (a0.w == b0.w);
        d = a1.x - b1.x; ssq = fmaf(d, d, ssq); eq = eq && (a1.x == b1.x);
        d = a1.y - b1.y; ssq = fmaf(d, d, ssq); eq = eq && (a1.y == b1.y);
        d = a1.z - b1.z; ssq = fmaf(d, d, ssq); eq = eq && (a1.z == b1.z);
        d = a1.w - b1.w; ssq = fmaf(d, d, ssq); eq = eq && (a1.w == b1.w);

        // wave-wide reductions (64 lanes)
        #pragma unroll
        for (int off = 32; off > 0; off >>= 1)
            ssq += __shfl_xor(ssq, off);
        const bool alleq = __all(eq);

        if (lane == 0) {
            float dx = sqrtf(ssq + EPS);
            float2 v1 = *reinterpret_cast<const float2*>(y1  + (size_t)row * 2);
            float2 v2 = *reinterpret_cast<const float2*>(y2  + (size_t)row * 2);
            float2 vp = *reinterpret_cast<const float2*>(yp1 + (size_t)row * 2);
            float e0 = v1.x - v2.x, e1 = v1.y - v2.y;
            float dy = sqrtf(fmaf(e0, e0, fmaf(e1, e1, EPS)));
            float w  = alleq ? 1.0f : dx;
            float t  = dx - dy;
            float g0 = v1.x - vp.x, g1 = v1.y - vp.y;
            acc += t * t / w + g0 * g0 + g1 * g1;
        }
    }

    __shared__ float s[BLOCK >> 6];
    if (lane == 0) s[wib] = acc;
    __syncthreads();
    if (threadIdx.x == 0) {
        float t = 0.0f;
        #pragma unroll
        for (int i = 0; i < (BLOCK >> 6); ++i) t += s[i];
        partial[blockIdx.x] = t;
    }
}

__global__ __launch_bounds__(BLOCK) void siamese_final(
    const float* __restrict__ partial, float* __restrict__ out, int n)
{
    float acc = 0.0f;
    for (int i = threadIdx.x; i < n; i += BLOCK) acc += partial[i];
    #pragma unroll
    for (int off = 32; off > 0; off >>= 1)
        acc += __shfl_xor(acc, off);
    __shared__ float s[BLOCK >> 6];
    const int lane = threadIdx.x & 63;
    const int wib  = threadIdx.x >> 6;
    if (lane == 0) s[wib] = acc;
    __syncthreads();
    if (threadIdx.x == 0) {
        float t = 0.0f;
        #pragma unroll
        for (int i = 0; i < (BLOCK >> 6); ++i) t += s[i];
        out[0] = t;   // overwrite, never accumulate: safe across graph replays
    }
}

extern "C" void kernel_launch(void* const* d_in, const int* in_sizes, int n_in,
                              void* d_out, int out_size, void* d_ws, size_t ws_size,
                              hipStream_t stream) {
    const float* x1  = (const float*)d_in[0];
    const float* x2  = (const float*)d_in[1];
    const float* y1  = (const float*)d_in[2];
    const float* y2  = (const float*)d_in[3];
    const float* yp1 = (const float*)d_in[4];
    float* out = (float*)d_out;
    float* partial = (float*)d_ws;          // NB floats = 4 KB scratch

    const int B = in_sizes[0] / DH;         // 65536

    siamese_partial<<<NB, BLOCK, 0, stream>>>(x1, x2, y1, y2, yp1, partial, B);
    siamese_final<<<1, BLOCK, 0, stream>>>(partial, out, NB);
}

// Round 2
// 46.801 us; speedup vs baseline: 1.0171x; 1.0171x over previous
//
#include <hip/hip_runtime.h>

#define DH 512
#define NB 2048
#define BLOCK 256
#define EPS 1e-6f

__global__ __launch_bounds__(BLOCK) void siamese_partial(
    const float* __restrict__ x1, const float* __restrict__ x2,
    const float* __restrict__ y1, const float* __restrict__ y2,
    const float* __restrict__ yp1, float* __restrict__ partial, int B)
{
    const int lane = threadIdx.x & 63;
    const int wib  = threadIdx.x >> 6;                       // wave in block
    const int wid  = blockIdx.x * (BLOCK >> 6) + wib;        // global wave id
    const int nw   = gridDim.x * (BLOCK >> 6);               // total waves

    float acc = 0.0f;

    for (int r0 = wid * 2; r0 < B; r0 += nw * 2) {
        const int r1 = r0 + 1;                               // B even; r1 < B always here
        const size_t base0 = (size_t)r0 * DH;
        const size_t base1 = (size_t)r1 * DH;
        const float4* pa0 = reinterpret_cast<const float4*>(x1 + base0) + lane * 2;
        const float4* pb0 = reinterpret_cast<const float4*>(x2 + base0) + lane * 2;
        const float4* pa1 = reinterpret_cast<const float4*>(x1 + base1) + lane * 2;
        const float4* pb1 = reinterpret_cast<const float4*>(x2 + base1) + lane * 2;

        // issue all 8 loads up front (ILP)
        float4 a00 = pa0[0], a01 = pa0[1];
        float4 b00 = pb0[0], b01 = pb0[1];
        float4 a10 = pa1[0], a11 = pa1[1];
        float4 b10 = pb1[0], b11 = pb1[1];

        float ssq0 = 0.0f, ssq1 = 0.0f;
        bool eq0 = true, eq1 = true;
        float d;
        d = a00.x - b00.x; ssq0 = fmaf(d, d, ssq0); eq0 = eq0 && (a00.x == b00.x);
        d = a00.y - b00.y; ssq0 = fmaf(d, d, ssq0); eq0 = eq0 && (a00.y == b00.y);
        d = a00.z - b00.z; ssq0 = fmaf(d, d, ssq0); eq0 = eq0 && (a00.z == b00.z);
        d = a00.w - b00.w; ssq0 = fmaf(d, d, ssq0); eq0 = eq0 && (a00.w == b00.w);
        d = a01.x - b01.x; ssq0 = fmaf(d, d, ssq0); eq0 = eq0 && (a01.x == b01.x);
        d = a01.y - b01.y; ssq0 = fmaf(d, d, ssq0); eq0 = eq0 && (a01.y == b01.y);
        d = a01.z - b01.z; ssq0 = fmaf(d, d, ssq0); eq0 = eq0 && (a01.z == b01.z);
        d = a01.w - b01.w; ssq0 = fmaf(d, d, ssq0); eq0 = eq0 && (a01.w == b01.w);
        d = a10.x - b10.x; ssq1 = fmaf(d, d, ssq1); eq1 = eq1 && (a10.x == b10.x);
        d = a10.y - b10.y; ssq1 = fmaf(d, d, ssq1); eq1 = eq1 && (a10.y == b10.y);
        d = a10.z - b10.z; ssq1 = fmaf(d, d, ssq1); eq1 = eq1 && (a10.z == b10.z);
        d = a10.w - b10.w; ssq1 = fmaf(d, d, ssq1); eq1 = eq1 && (a10.w == b10.w);
        d = a11.x - b11.x; ssq1 = fmaf(d, d, ssq1); eq1 = eq1 && (a11.x == b11.x);
        d = a11.y - b11.y; ssq1 = fmaf(d, d, ssq1); eq1 = eq1 && (a11.y == b11.y);
        d = a11.z - b11.z; ssq1 = fmaf(d, d, ssq1); eq1 = eq1 && (a11.z == b11.z);
        d = a11.w - b11.w; ssq1 = fmaf(d, d, ssq1); eq1 = eq1 && (a11.w == b11.w);

        // two interleaved wave-wide reductions (64 lanes)
        #pragma unroll
        for (int off = 32; off > 0; off >>= 1) {
            ssq0 += __shfl_xor(ssq0, off);
            ssq1 += __shfl_xor(ssq1, off);
        }
        const bool al0 = __all(eq0);
        const bool al1 = __all(eq1);

        // epilogue: lanes 0 and 1 handle one row each, in parallel
        if (lane < 2) {
            const int   row = (lane == 0) ? r0   : r1;
            const float ssq = (lane == 0) ? ssq0 : ssq1;
            const bool  al  = (lane == 0) ? al0  : al1;
            float dx = sqrtf(ssq + EPS);
            float2 v1 = *reinterpret_cast<const float2*>(y1  + (size_t)row * 2);
            float2 v2 = *reinterpret_cast<const float2*>(y2  + (size_t)row * 2);
            float2 vp = *reinterpret_cast<const float2*>(yp1 + (size_t)row * 2);
            float e0 = v1.x - v2.x, e1 = v1.y - v2.y;
            float dy = sqrtf(fmaf(e0, e0, fmaf(e1, e1, EPS)));
            float w  = al ? 1.0f : dx;
            float t  = dx - dy;
            float g0 = v1.x - vp.x, g1 = v1.y - vp.y;
            acc += t * t / w + g0 * g0 + g1 * g1;
        }
    }

    // once-per-wave reduction of acc (lanes 0 and 1 hold partials)
    #pragma unroll
    for (int off = 32; off > 0; off >>= 1)
        acc += __shfl_xor(acc, off);

    __shared__ float s[BLOCK >> 6];
    if (lane == 0) s[wib] = acc;
    __syncthreads();
    if (threadIdx.x == 0) {
        float t = 0.0f;
        #pragma unroll
        for (int i = 0; i < (BLOCK >> 6); ++i) t += s[i];
        partial[blockIdx.x] = t;
    }
}

__global__ __launch_bounds__(BLOCK) void siamese_final(
    const float* __restrict__ partial, float* __restrict__ out, int n)
{
    float acc = 0.0f;
    for (int i = threadIdx.x; i < n; i += BLOCK) acc += partial[i];
    #pragma unroll
    for (int off = 32; off > 0; off >>= 1)
        acc += __shfl_xor(acc, off);
    __shared__ float s[BLOCK >> 6];
    const int lane = threadIdx.x & 63;
    const int wib  = threadIdx.x >> 6;
    if (lane == 0) s[wib] = acc;
    __syncthreads();
    if (threadIdx.x == 0) {
        float t = 0.0f;
        #pragma unroll
        for (int i = 0; i < (BLOCK >> 6); ++i) t += s[i];
        out[0] = t;   // overwrite, never accumulate: safe across graph replays
    }
}

extern "C" void kernel_launch(void* const* d_in, const int* in_sizes, int n_in,
                              void* d_out, int out_size, void* d_ws, size_t ws_size,
                              hipStream_t stream) {
    const float* x1  = (const float*)d_in[0];
    const float* x2  = (const float*)d_in[1];
    const float* y1  = (const float*)d_in[2];
    const float* y2  = (const float*)d_in[3];
    const float* yp1 = (const float*)d_in[4];
    float* out = (float*)d_out;
    float* partial = (float*)d_ws;          // NB floats = 8 KB scratch

    const int B = in_sizes[0] / DH;         // 65536

    siamese_partial<<<NB, BLOCK, 0, stream>>>(x1, x2, y1, y2, yp1, partial, B);
    siamese_final<<<1, BLOCK, 0, stream>>>(partial, out, NB);
}